// Round 8
// baseline (10570.634 us; speedup 1.0000x reference)
//
#include <hip/hip_runtime.h>

#define BB 64
#define TT 128
#define SS 256
#define HH 2048
#define G4H 8192
#define KSUM 4096   // per-step GEMM K: [U_h | C_ctx]
#define NKK_G 128   // KSUM/32
#define NKK_A 64    // HH/32

typedef __attribute__((ext_vector_type(4))) float f32x4;
typedef __attribute__((ext_vector_type(8))) _Float16 h16x8;
typedef __attribute__((ext_vector_type(4))) _Float16 h16x4;
typedef __attribute__((ext_vector_type(2))) _Float16 h16x2;

typedef __attribute__((address_space(1))) const void GV;
typedef __attribute__((address_space(3))) void SV;

__device__ __forceinline__ f32x4 mfma16(h16x8 a, h16x8 b, f32x4 c) {
  return __builtin_amdgcn_mfma_f32_16x16x32_f16(a, b, c, 0, 0, 0);
}

__device__ __forceinline__ float fast_exp2(float x) { return __builtin_amdgcn_exp2f(x); }
__device__ __forceinline__ float fast_rcp(float x) { return __builtin_amdgcn_rcpf(x); }
__device__ __forceinline__ float fast_tanh(float x) {
  float e = fast_exp2(x * 2.8853900817779268f);
  return 1.0f - 2.0f * fast_rcp(e + 1.0f);
}
__device__ __forceinline__ float fast_sig(float x) {
  return fast_rcp(1.0f + fast_exp2(x * -1.4426950408889634f));
}

// ---------------- prep kernels ----------------

__global__ void cvt_f32_to_f16(const float* __restrict__ src, _Float16* __restrict__ dst, int n4) {
  int i = blockIdx.x * blockDim.x + threadIdx.x;
  int stride = gridDim.x * blockDim.x;
  for (; i < n4; i += stride) {
    f32x4 v = reinterpret_cast<const f32x4*>(src)[i];
    h16x4 h;
    h[0] = (_Float16)v[0]; h[1] = (_Float16)v[1];
    h[2] = (_Float16)v[2]; h[3] = (_Float16)v[3];
    reinterpret_cast<h16x4*>(dst)[i] = h;
  }
}

// kh[b,s,k] = f16(enc_keys[b,s,k] + b_attr[k])
__global__ void cvt_keys(const float* __restrict__ src, const float* __restrict__ battr,
                         _Float16* __restrict__ dst, int n8) {
  int i = blockIdx.x * blockDim.x + threadIdx.x;
  int stride = gridDim.x * blockDim.x;
  for (; i < n8; i += stride) {
    size_t base = (size_t)i * 8;
    int k = (int)(base & (HH - 1));
    f32x4 v0 = *reinterpret_cast<const f32x4*>(src + base);
    f32x4 v1 = *reinterpret_cast<const f32x4*>(src + base + 4);
    f32x4 b0 = *reinterpret_cast<const f32x4*>(battr + k);
    f32x4 b1 = *reinterpret_cast<const f32x4*>(battr + k + 4);
    h16x8 o;
#pragma unroll
    for (int j = 0; j < 4; ++j) { o[j] = (_Float16)(v0[j] + b0[j]); o[4 + j] = (_Float16)(v1[j] + b1[j]); }
    *reinterpret_cast<h16x8*>(dst + base) = o;
  }
}

// yT[t][b][i] = f16(y[b][t][i])  (row index t*64+b matches Gy rows)
__global__ void transpose_y(const float* __restrict__ y, _Float16* __restrict__ yT) {
  int blk = blockIdx.x;             // B*T blocks
  int b = blk / TT, t = blk - b * TT;
  int i = threadIdx.x * 8;
  const float* s = y + ((size_t)b * TT + t) * HH + i;
  f32x4 v0 = *reinterpret_cast<const f32x4*>(s);
  f32x4 v1 = *reinterpret_cast<const f32x4*>(s + 4);
  h16x8 o;
#pragma unroll
  for (int j = 0; j < 4; ++j) { o[j] = (_Float16)v0[j]; o[4 + j] = (_Float16)v1[j]; }
  *reinterpret_cast<h16x8*>(yT + ((size_t)t * BB + b) * HH + i) = o;
}

// Swizzled B layout: frag(ct, kk, lane, i) = W[ct*16 + (lane&15)][kk*32 + (lane>>4)*8 + i]
// stored at ((ct*NKK + kk)*64 + lane)*8 + i (halves). Wave load at (ct,kk) = 1KB contiguous.

// Wgs: cols n' = 4*h + g (gate-interleaved), rows = [U_h | C_ctx] over K=4096.
__global__ void build_wgs(const float* __restrict__ U, const float* __restrict__ Cc,
                          const float* __restrict__ bias,
                          _Float16* __restrict__ Wgs, float* __restrict__ bperm) {
  int ct = blockIdx.x;              // 0..511
  int kw = threadIdx.x >> 6, l = threadIdx.x & 63;
  int c = ct * 16 + (l & 15);
  int g = c & 3, hidx = c >> 2;
  size_t srow = ((size_t)g * HH + hidx) * HH;
  const float* seg[2] = {U + srow, Cc + srow};
  int koff_lane = (l >> 4) * 8;
  for (int j = 0; j < 32; ++j) {
    int kk = j * 4 + kw;            // 0..127; seg by kk>>6 == j>>4
    const float* s = seg[j >> 4] + (kk & 63) * 32 + koff_lane;
    f32x4 v0 = *reinterpret_cast<const f32x4*>(s);
    f32x4 v1 = *reinterpret_cast<const f32x4*>(s + 4);
    h16x8 o;
#pragma unroll
    for (int q = 0; q < 4; ++q) { o[q] = (_Float16)v0[q]; o[4 + q] = (_Float16)v1[q]; }
    *reinterpret_cast<h16x8*>(Wgs + (((size_t)ct * NKK_G + kk) * 64 + l) * 8) = o;
  }
  if (threadIdx.x < 16) bperm[c] = bias[g * HH + hidx];
}

// Wys: W_y fragments, cols in n' = 4*h + g order, K = 2048.
__global__ void build_wys(const float* __restrict__ Wy, _Float16* __restrict__ Wys) {
  int ct = blockIdx.x;              // 0..511
  int kw = threadIdx.x >> 6, l = threadIdx.x & 63;
  int c = ct * 16 + (l & 15);
  int g = c & 3, hidx = c >> 2;
  const float* row = Wy + ((size_t)g * HH + hidx) * HH + (l >> 4) * 8;
  for (int j = 0; j < 16; ++j) {
    int kk = j * 4 + kw;            // 0..63
    const float* s = row + kk * 32;
    f32x4 v0 = *reinterpret_cast<const f32x4*>(s);
    f32x4 v1 = *reinterpret_cast<const f32x4*>(s + 4);
    h16x8 o;
#pragma unroll
    for (int q = 0; q < 4; ++q) { o[q] = (_Float16)v0[q]; o[4 + q] = (_Float16)v1[q]; }
    *reinterpret_cast<h16x8*>(Wys + (((size_t)ct * NKK_A + kk) * 64 + l) * 8) = o;
  }
}

// Wahs from W_attr [K=2048 rows][H=2048], cols of the GEMM are W_attr rows.
__global__ void build_wahs(const float* __restrict__ W, _Float16* __restrict__ Wahs) {
  int ct = blockIdx.x;              // 0..127
  int kw = threadIdx.x >> 6, l = threadIdx.x & 63;
  int c = ct * 16 + (l & 15);
  const float* row = W + (size_t)c * HH + (l >> 4) * 8;
  for (int j = 0; j < 16; ++j) {
    int kk = j * 4 + kw;            // 0..63
    const float* s = row + kk * 32;
    f32x4 v0 = *reinterpret_cast<const f32x4*>(s);
    f32x4 v1 = *reinterpret_cast<const f32x4*>(s + 4);
    h16x8 o;
#pragma unroll
    for (int q = 0; q < 4; ++q) { o[q] = (_Float16)v0[q]; o[4 + q] = (_Float16)v1[q]; }
    *reinterpret_cast<h16x8*>(Wahs + (((size_t)ct * NKK_A + kk) * 64 + l) * 8) = o;
  }
}

// One-time Gy = yT @ Wys + bias: M=8192 (t*64+b), N=8192 (n'), K=2048, f16 out.
__global__ void __launch_bounds__(512)
gy_gemm(const _Float16* __restrict__ yT, const _Float16* __restrict__ Wys,
        const float* __restrict__ bperm, _Float16* __restrict__ Gy) {
  int tid = threadIdx.x;
  int w = tid >> 6, l = tid & 63;
  int wr = w >> 2, wc = w & 3;
  int br = blockIdx.x & 63, bc = blockIdx.x >> 6;
  const _Float16* abase = yT + ((size_t)(br * 128 + wr * 64 + (l & 15))) * HH + (l >> 4) * 8;
  const _Float16* bbase = Wys + ((size_t)(bc * 16 + wc * 4) * NKK_A) * 512 + l * 8;
  f32x4 acc[4][4] = {};
#pragma unroll 1
  for (int kk = 0; kk < NKK_A; ++kk) {
    h16x8 a0 = *reinterpret_cast<const h16x8*>(abase + (size_t)0 * 16 * HH + kk * 32);
    h16x8 a1 = *reinterpret_cast<const h16x8*>(abase + (size_t)1 * 16 * HH + kk * 32);
    h16x8 a2 = *reinterpret_cast<const h16x8*>(abase + (size_t)2 * 16 * HH + kk * 32);
    h16x8 a3 = *reinterpret_cast<const h16x8*>(abase + (size_t)3 * 16 * HH + kk * 32);
    h16x8 b0 = *reinterpret_cast<const h16x8*>(bbase + ((size_t)0 * NKK_A + kk) * 512);
    h16x8 b1 = *reinterpret_cast<const h16x8*>(bbase + ((size_t)1 * NKK_A + kk) * 512);
    h16x8 b2 = *reinterpret_cast<const h16x8*>(bbase + ((size_t)2 * NKK_A + kk) * 512);
    h16x8 b3 = *reinterpret_cast<const h16x8*>(bbase + ((size_t)3 * NKK_A + kk) * 512);
    acc[0][0] = mfma16(a0, b0, acc[0][0]); acc[0][1] = mfma16(a0, b1, acc[0][1]);
    acc[0][2] = mfma16(a0, b2, acc[0][2]); acc[0][3] = mfma16(a0, b3, acc[0][3]);
    acc[1][0] = mfma16(a1, b0, acc[1][0]); acc[1][1] = mfma16(a1, b1, acc[1][1]);
    acc[1][2] = mfma16(a1, b2, acc[1][2]); acc[1][3] = mfma16(a1, b3, acc[1][3]);
    acc[2][0] = mfma16(a2, b0, acc[2][0]); acc[2][1] = mfma16(a2, b1, acc[2][1]);
    acc[2][2] = mfma16(a2, b2, acc[2][2]); acc[2][3] = mfma16(a2, b3, acc[2][3]);
    acc[3][0] = mfma16(a3, b0, acc[3][0]); acc[3][1] = mfma16(a3, b1, acc[3][1]);
    acc[3][2] = mfma16(a3, b2, acc[3][2]); acc[3][3] = mfma16(a3, b3, acc[3][3]);
  }
#pragma unroll
  for (int q = 0; q < 4; ++q) {
#pragma unroll
    for (int cc = 0; cc < 4; ++cc) {
      int col = (bc * 16 + wc * 4 + cc) * 16 + (l & 15);
      float bv = bperm[col];
      int r0 = br * 128 + wr * 64 + q * 16 + (l >> 4) * 4;
#pragma unroll
      for (int r = 0; r < 4; ++r)
        Gy[(size_t)(r0 + r) * G4H + col] = (_Float16)(acc[q][cc][r] + bv);
    }
  }
}

__global__ void init_state(float* __restrict__ cst, _Float16* __restrict__ hA) {
  int i = blockIdx.x * blockDim.x + threadIdx.x;
  if (i < BB * HH) {
    cst[i] = 0.0f;
    hA[i] = (_Float16)0.0f;
  }
}

// ---------------- per-step kernels ----------------

// q[b,k] = sum_j h[b,j]*W_attr[k,j]  (M=64, N=2048, K=2048), bias folded into kh.
__global__ void qgemm(const _Float16* __restrict__ hIn, const _Float16* __restrict__ Wahs,
                      _Float16* __restrict__ qh) {
  int w = threadIdx.x >> 6, l = threadIdx.x & 63;
  int ct = blockIdx.x;
  const _Float16* bp = Wahs + (size_t)ct * (NKK_A * 512) + l * 8;
  const _Float16* ap = hIn + (size_t)(w * 16 + (l & 15)) * HH + (l >> 4) * 8;
  f32x4 acc0 = {0.f, 0.f, 0.f, 0.f}, acc1 = {0.f, 0.f, 0.f, 0.f};
  f32x4 acc2 = {0.f, 0.f, 0.f, 0.f}, acc3 = {0.f, 0.f, 0.f, 0.f};
#pragma unroll 2
  for (int kk = 0; kk < NKK_A; kk += 4) {
    h16x8 b0 = *reinterpret_cast<const h16x8*>(bp + (size_t)kk * 512);
    h16x8 b1 = *reinterpret_cast<const h16x8*>(bp + (size_t)(kk + 1) * 512);
    h16x8 b2 = *reinterpret_cast<const h16x8*>(bp + (size_t)(kk + 2) * 512);
    h16x8 b3 = *reinterpret_cast<const h16x8*>(bp + (size_t)(kk + 3) * 512);
    h16x8 a0 = *reinterpret_cast<const h16x8*>(ap + kk * 32);
    h16x8 a1 = *reinterpret_cast<const h16x8*>(ap + (kk + 1) * 32);
    h16x8 a2 = *reinterpret_cast<const h16x8*>(ap + (kk + 2) * 32);
    h16x8 a3 = *reinterpret_cast<const h16x8*>(ap + (kk + 3) * 32);
    acc0 = mfma16(a0, b0, acc0);
    acc1 = mfma16(a1, b1, acc1);
    acc2 = mfma16(a2, b2, acc2);
    acc3 = mfma16(a3, b3, acc3);
  }
  f32x4 acc = (acc0 + acc1) + (acc2 + acc3);
  int col = ct * 16 + (l & 15);
  int rbase = w * 16 + (l >> 4) * 4;
#pragma unroll
  for (int r = 0; r < 4; ++r)
    qh[(size_t)(rbase + r) * HH + col] = (_Float16)acc[r];
}

// p[b,s] = mask*exp(sum_k V[k]*tanh(kh[b,s,k] + q[b,k]))  (unnormalized softmax weight;
// masked -> 0 exactly, matching exp(-1e5)=0). Fully unrolled, no runtime-indexed arrays.
__global__ void energies(const _Float16* __restrict__ kh, const _Float16* __restrict__ qh,
                         const _Float16* __restrict__ vh, const float* __restrict__ mask,
                         float* __restrict__ pbuf) {
  int b = blockIdx.x >> 5, sg = blockIdx.x & 31;
  int tid = threadIdx.x;
  int sl = tid >> 5, ln = tid & 31;
  int s = sg * 8 + sl;
  const _Float16* row = kh + (size_t)(b * SS + s) * HH + ln * 8;
  const _Float16* qrow = qh + (size_t)b * HH + ln * 8;
  const _Float16* vrow = vh + ln * 8;
  float acc = 0.0f;
#pragma unroll
  for (int ch = 0; ch < 8; ++ch) {
    h16x8 k8 = *reinterpret_cast<const h16x8*>(row + ch * 256);
    h16x8 q8 = *reinterpret_cast<const h16x8*>(qrow + ch * 256);
    h16x8 v8 = *reinterpret_cast<const h16x8*>(vrow + ch * 256);
    h16x8 x8 = k8 + q8;
#pragma unroll
    for (int j = 0; j < 8; ++j) {
      acc += (float)v8[j] * fast_tanh((float)x8[j]);
    }
  }
#pragma unroll
  for (int off = 16; off > 0; off >>= 1) acc += __shfl_xor(acc, off);
  if (ln == 0) {
    float m = mask[b * SS + s];
    pbuf[b * SS + s] = m * fast_exp2(acc * 1.4426950408889634f);
  }
}

// ctx[b,c] = (sum_s p[s]*ev[b,s,c]) / sum_s p[s]. grid = B*4 x 512 thr;
// 8 waves each own 32 s-rows (2 waves/SIMD, 32-deep 16B/lane load loop).
__global__ void __launch_bounds__(512)
ctx_softmax(const float* __restrict__ pbuf, const _Float16* __restrict__ evh,
            _Float16* __restrict__ ctxh, float* __restrict__ outCtx, int t) {
  __shared__ float pb[SS];
  __shared__ float red[4];
  __shared__ float pf[8][512];
  int b = blockIdx.x >> 2, cq = blockIdx.x & 3;
  int tid = threadIdx.x;
  if (tid < SS) {
    float p = pbuf[b * SS + tid];
    pb[tid] = p;
    float ws = p;
#pragma unroll
    for (int off = 32; off > 0; off >>= 1) ws += __shfl_xor(ws, off);
    if ((tid & 63) == 0) red[tid >> 6] = ws;
  }
  __syncthreads();
  float rs = fast_rcp(red[0] + red[1] + red[2] + red[3]);
  int sg = tid >> 6, cs = tid & 63;
  const _Float16* base = evh + ((size_t)b * SS + sg * 32) * HH + cq * 512 + cs * 8;
  float acc[8] = {0.f, 0.f, 0.f, 0.f, 0.f, 0.f, 0.f, 0.f};
#pragma unroll 8
  for (int s = 0; s < 32; ++s) {
    h16x8 v = *reinterpret_cast<const h16x8*>(base + (size_t)s * HH);
    float ps = pb[sg * 32 + s];
#pragma unroll
    for (int j = 0; j < 8; ++j) acc[j] += ps * (float)v[j];
  }
#pragma unroll
  for (int j = 0; j < 8; ++j) pf[sg][cs * 8 + j] = acc[j];
  __syncthreads();
  {
    int c = tid;                    // 0..511
    float sum = pf[0][c] + pf[1][c] + pf[2][c] + pf[3][c]
              + pf[4][c] + pf[5][c] + pf[6][c] + pf[7][c];
    float val = sum * rs;
    outCtx[((size_t)b * TT + t) * HH + cq * 512 + c] = val;
    ctxh[(size_t)b * HH + cq * 512 + c] = (_Float16)val;
  }
}

// gates = Gy[t] (acc init, has y@Wy^T + bias) + h@U^T + ctx@C^T, then fused LSTM cell.
// grid = 256 x 512 thr (8 waves = 4 mq x 2 cth). B double-buffered in LDS via
// global_load_lds; Gy acc-init overlaps the first staging wait.
__global__ void __launch_bounds__(512)
gates_cell(const _Float16* __restrict__ hIn, const _Float16* __restrict__ ctxh,
           const _Float16* __restrict__ Gy, const _Float16* __restrict__ Wgs,
           float* __restrict__ cst, float* __restrict__ outH,
           _Float16* __restrict__ hOut, int t) {
  __shared__ _Float16 Bsm[2][2][16][512];   // [buf][ctgl][slot][lane*8] = 64 KB
  __shared__ float glds[64 * 33];
  int tid = threadIdx.x;
  int w = tid >> 6, l = tid & 63;
  int mq = w >> 1, cth = w & 1;
  int cb = blockIdx.x;

  // stage chunk c (16 kk-slots x 2 ctg = 32 KB) into Bsm[buf]
  auto STAGE = [&](int buf, int c) {
#pragma unroll
    for (int u = 0; u < 4; ++u) {
      int idx = w * 4 + u;            // 0..31
      int ctgl = idx >> 4, slot = idx & 15;
      const _Float16* g = Wgs + (((size_t)(cb * 2 + ctgl) * NKK_G + c * 16 + slot) * 64 + l) * 8;
      __builtin_amdgcn_global_load_lds((GV*)g, (SV*)&Bsm[buf][ctgl][slot][0], 16, 0, 0);
    }
  };

  STAGE(0, 0);

  // acc init from Gy (rows t*64+b, cols n') — overlaps the staging latency.
  int col = cb * 32 + cth * 16 + (l & 15);
  int rb = mq * 16 + (l >> 4) * 4;
  f32x4 acc;
  {
    const _Float16* gy = Gy + ((size_t)(t * 64 + rb)) * G4H + col;
    acc[0] = (float)gy[0];
    acc[1] = (float)gy[(size_t)G4H];
    acc[2] = (float)gy[(size_t)2 * G4H];
    acc[3] = (float)gy[(size_t)3 * G4H];
  }

  size_t arow = (size_t)(mq * 16 + (l & 15)) * HH + (l >> 4) * 8;

  __syncthreads();
  int buf = 0;
#pragma unroll 1
  for (int c = 0; c < 8; ++c) {
    if (c < 7) STAGE(buf ^ 1, c + 1);
    const _Float16* a = (c < 4 ? hIn : ctxh) + arow;
    int kloc = (c & 3) * 16;
#pragma unroll
    for (int s = 0; s < 16; ++s) {
      h16x8 bf = *reinterpret_cast<const h16x8*>(&Bsm[buf][cth][s][l * 8]);
      h16x8 af = *reinterpret_cast<const h16x8*>(a + (kloc + s) * 32);
      acc = mfma16(af, bf, acc);
    }
    __syncthreads();   // drains staging vmcnt + lgkm; all waves done with Bsm[buf]
    buf ^= 1;
  }

  int lcol = cth * 16 + (l & 15);
#pragma unroll
  for (int r = 0; r < 4; ++r)
    glds[(rb + r) * 33 + lcol] = acc[r];
  __syncthreads();
  // cell: 512 threads, one (b, h) each; block covers 8 h-indices.
  int b = tid >> 3, hl = tid & 7;
  int h0 = cb * 8;
  float gi = glds[b * 33 + hl * 4 + 0];
  float gf = glds[b * 33 + hl * 4 + 1];
  float go = glds[b * 33 + hl * 4 + 2];
  float gc = glds[b * 33 + hl * 4 + 3];
  float ig = fast_sig(gi), fg = fast_sig(gf), og = fast_sig(go);
  int ci = b * HH + h0 + hl;
  float cN = ig * fast_tanh(gc) + fg * cst[ci];
  float hN = og * fast_tanh(cN);
  cst[ci] = cN;
  outH[((size_t)b * TT + t) * HH + h0 + hl] = hN;
  hOut[ci] = (_Float16)hN;
}

// ---------------- launcher ----------------

extern "C" void kernel_launch(void* const* d_in, const int* in_sizes, int n_in,
                              void* d_out, int out_size, void* d_ws, size_t ws_size,
                              hipStream_t stream) {
  const float* enc_keys   = (const float*)d_in[0];
  const float* enc_values = (const float*)d_in[1];
  const float* enc_mask   = (const float*)d_in[2];
  const float* y          = (const float*)d_in[3];
  const float* W_attr     = (const float*)d_in[4];
  const float* V_attr     = (const float*)d_in[5];
  const float* b_attr     = (const float*)d_in[6];
  const float* W_y        = (const float*)d_in[7];
  const float* U_h        = (const float*)d_in[8];
  const float* C_ctx      = (const float*)d_in[9];
  const float* bias       = (const float*)d_in[10];

  char* ws = (char*)d_ws;
  size_t off = 0;
  auto alloc = [&](size_t bytes) {
    void* p = ws + off;
    off += (bytes + 255) & ~(size_t)255;
    return p;
  };
  _Float16* kh   = (_Float16*)alloc((size_t)BB * SS * HH * 2);
  _Float16* evh  = (_Float16*)alloc((size_t)BB * SS * HH * 2);
  _Float16* Wahs = (_Float16*)alloc((size_t)HH * HH * 2);
  _Float16* Wgs  = (_Float16*)alloc((size_t)G4H * KSUM * 2);
  _Float16* Wys  = (_Float16*)alloc((size_t)G4H * HH * 2);
  _Float16* Gy   = (_Float16*)alloc((size_t)BB * TT * G4H * 2);
  _Float16* yTh  = (_Float16*)alloc((size_t)BB * TT * HH * 2);
  _Float16* hA   = (_Float16*)alloc((size_t)BB * HH * 2);
  _Float16* hB   = (_Float16*)alloc((size_t)BB * HH * 2);
  _Float16* ctxh = (_Float16*)alloc((size_t)BB * HH * 2);
  _Float16* qh   = (_Float16*)alloc((size_t)BB * HH * 2);
  _Float16* vhb  = (_Float16*)alloc((size_t)HH * 2);
  float* pbuf    = (float*)alloc((size_t)BB * SS * 4);
  float* cst     = (float*)alloc((size_t)BB * HH * 4);
  float* bperm   = (float*)alloc((size_t)G4H * 4);
  (void)ws_size; (void)in_sizes; (void)n_in; (void)out_size;

  float* outH = (float*)d_out;
  float* outCtx = outH + (size_t)BB * TT * HH;

  cvt_keys<<<2048, 256, 0, stream>>>(enc_keys, b_attr, kh, BB * SS * HH / 8);
  cvt_f32_to_f16<<<2048, 256, 0, stream>>>(enc_values, evh, BB * SS * HH / 4);
  cvt_f32_to_f16<<<2, 256, 0, stream>>>(V_attr, vhb, HH / 4);
  build_wahs<<<HH / 16, 256, 0, stream>>>(W_attr, Wahs);
  build_wgs<<<G4H / 16, 256, 0, stream>>>(U_h, C_ctx, bias, Wgs, bperm);
  build_wys<<<G4H / 16, 256, 0, stream>>>(W_y, Wys);
  transpose_y<<<BB * TT, 256, 0, stream>>>(y, yTh);
  gy_gemm<<<2048, 512, 0, stream>>>(yTh, Wys, bperm, Gy);
  init_state<<<(BB * HH + 255) / 256, 256, 0, stream>>>(cst, hA);

  for (int t = 0; t < TT; ++t) {
    const _Float16* hIn = (t & 1) ? hB : hA;
    _Float16* hOut      = (t & 1) ? hA : hB;
    qgemm<<<HH / 16, 256, 0, stream>>>(hIn, Wahs, qh);
    energies<<<BB * SS / 8, 256, 0, stream>>>(kh, qh, vhb, enc_mask, pbuf);
    ctx_softmax<<<BB * 4, 512, 0, stream>>>(pbuf, evh, ctxh, outCtx, t);
    gates_cell<<<G4H / 32, 512, 0, stream>>>(hIn, ctxh, Gy, Wgs, cst, outH, hOut, t);
  }
}

// Round 9
// 10412.160 us; speedup vs baseline: 1.0152x; 1.0152x over previous
//
#include <hip/hip_runtime.h>

#define BB 64
#define TT 128
#define SS 256
#define HH 2048
#define G4H 8192
#define KSUM 4096   // per-step GEMM K: [U_h | C_ctx]
#define NKK_G 128   // KSUM/32
#define NKK_A 64    // HH/32

typedef __attribute__((ext_vector_type(4))) float f32x4;
typedef __attribute__((ext_vector_type(8))) _Float16 h16x8;
typedef __attribute__((ext_vector_type(4))) _Float16 h16x4;
typedef __attribute__((ext_vector_type(2))) _Float16 h16x2;

typedef __attribute__((address_space(1))) const void GV;
typedef __attribute__((address_space(3))) void SV;

__device__ __forceinline__ f32x4 mfma16(h16x8 a, h16x8 b, f32x4 c) {
  return __builtin_amdgcn_mfma_f32_16x16x32_f16(a, b, c, 0, 0, 0);
}

__device__ __forceinline__ float fast_exp2(float x) { return __builtin_amdgcn_exp2f(x); }
__device__ __forceinline__ float fast_rcp(float x) { return __builtin_amdgcn_rcpf(x); }
__device__ __forceinline__ float fast_tanh(float x) {
  float e = fast_exp2(x * 2.8853900817779268f);
  return 1.0f - 2.0f * fast_rcp(e + 1.0f);
}
__device__ __forceinline__ float fast_sig(float x) {
  return fast_rcp(1.0f + fast_exp2(x * -1.4426950408889634f));
}

// ---------------- prep kernels ----------------

__global__ void cvt_f32_to_f16(const float* __restrict__ src, _Float16* __restrict__ dst, int n4) {
  int i = blockIdx.x * blockDim.x + threadIdx.x;
  int stride = gridDim.x * blockDim.x;
  for (; i < n4; i += stride) {
    f32x4 v = reinterpret_cast<const f32x4*>(src)[i];
    h16x4 h;
    h[0] = (_Float16)v[0]; h[1] = (_Float16)v[1];
    h[2] = (_Float16)v[2]; h[3] = (_Float16)v[3];
    reinterpret_cast<h16x4*>(dst)[i] = h;
  }
}

// kh[b,s,k] = f16(enc_keys[b,s,k] + b_attr[k])
__global__ void cvt_keys(const float* __restrict__ src, const float* __restrict__ battr,
                         _Float16* __restrict__ dst, int n8) {
  int i = blockIdx.x * blockDim.x + threadIdx.x;
  int stride = gridDim.x * blockDim.x;
  for (; i < n8; i += stride) {
    size_t base = (size_t)i * 8;
    int k = (int)(base & (HH - 1));
    f32x4 v0 = *reinterpret_cast<const f32x4*>(src + base);
    f32x4 v1 = *reinterpret_cast<const f32x4*>(src + base + 4);
    f32x4 b0 = *reinterpret_cast<const f32x4*>(battr + k);
    f32x4 b1 = *reinterpret_cast<const f32x4*>(battr + k + 4);
    h16x8 o;
#pragma unroll
    for (int j = 0; j < 4; ++j) { o[j] = (_Float16)(v0[j] + b0[j]); o[4 + j] = (_Float16)(v1[j] + b1[j]); }
    *reinterpret_cast<h16x8*>(dst + base) = o;
  }
}

// yT[t][b][i] = f16(y[b][t][i])  (row index t*64+b matches Gy rows)
__global__ void transpose_y(const float* __restrict__ y, _Float16* __restrict__ yT) {
  int blk = blockIdx.x;             // B*T blocks
  int b = blk / TT, t = blk - b * TT;
  int i = threadIdx.x * 8;
  const float* s = y + ((size_t)b * TT + t) * HH + i;
  f32x4 v0 = *reinterpret_cast<const f32x4*>(s);
  f32x4 v1 = *reinterpret_cast<const f32x4*>(s + 4);
  h16x8 o;
#pragma unroll
  for (int j = 0; j < 4; ++j) { o[j] = (_Float16)v0[j]; o[4 + j] = (_Float16)v1[j]; }
  *reinterpret_cast<h16x8*>(yT + ((size_t)t * BB + b) * HH + i) = o;
}

// Swizzled B layout: frag(ct, kk, lane, i) = W[ct*16 + (lane&15)][kk*32 + (lane>>4)*8 + i]
// stored at ((ct*NKK + kk)*64 + lane)*8 + i (halves). Wave load at (ct,kk) = 1KB contiguous.

// Wgs: cols n' = 4*h + g (gate-interleaved), rows = [U_h | C_ctx] over K=4096.
__global__ void build_wgs(const float* __restrict__ U, const float* __restrict__ Cc,
                          const float* __restrict__ bias,
                          _Float16* __restrict__ Wgs, float* __restrict__ bperm) {
  int ct = blockIdx.x;              // 0..511
  int kw = threadIdx.x >> 6, l = threadIdx.x & 63;
  int c = ct * 16 + (l & 15);
  int g = c & 3, hidx = c >> 2;
  size_t srow = ((size_t)g * HH + hidx) * HH;
  const float* seg[2] = {U + srow, Cc + srow};
  int koff_lane = (l >> 4) * 8;
  for (int j = 0; j < 32; ++j) {
    int kk = j * 4 + kw;            // 0..127; seg by kk>>6 == j>>4
    const float* s = seg[j >> 4] + (kk & 63) * 32 + koff_lane;
    f32x4 v0 = *reinterpret_cast<const f32x4*>(s);
    f32x4 v1 = *reinterpret_cast<const f32x4*>(s + 4);
    h16x8 o;
#pragma unroll
    for (int q = 0; q < 4; ++q) { o[q] = (_Float16)v0[q]; o[4 + q] = (_Float16)v1[q]; }
    *reinterpret_cast<h16x8*>(Wgs + (((size_t)ct * NKK_G + kk) * 64 + l) * 8) = o;
  }
  if (threadIdx.x < 16) bperm[c] = bias[g * HH + hidx];
}

// Wys: W_y fragments, cols in n' = 4*h + g order, K = 2048.
__global__ void build_wys(const float* __restrict__ Wy, _Float16* __restrict__ Wys) {
  int ct = blockIdx.x;              // 0..511
  int kw = threadIdx.x >> 6, l = threadIdx.x & 63;
  int c = ct * 16 + (l & 15);
  int g = c & 3, hidx = c >> 2;
  const float* row = Wy + ((size_t)g * HH + hidx) * HH + (l >> 4) * 8;
  for (int j = 0; j < 16; ++j) {
    int kk = j * 4 + kw;            // 0..63
    const float* s = row + kk * 32;
    f32x4 v0 = *reinterpret_cast<const f32x4*>(s);
    f32x4 v1 = *reinterpret_cast<const f32x4*>(s + 4);
    h16x8 o;
#pragma unroll
    for (int q = 0; q < 4; ++q) { o[q] = (_Float16)v0[q]; o[4 + q] = (_Float16)v1[q]; }
    *reinterpret_cast<h16x8*>(Wys + (((size_t)ct * NKK_A + kk) * 64 + l) * 8) = o;
  }
}

// Wahs from W_attr [K=2048 rows][H=2048], cols of the GEMM are W_attr rows.
__global__ void build_wahs(const float* __restrict__ W, _Float16* __restrict__ Wahs) {
  int ct = blockIdx.x;              // 0..127
  int kw = threadIdx.x >> 6, l = threadIdx.x & 63;
  int c = ct * 16 + (l & 15);
  const float* row = W + (size_t)c * HH + (l >> 4) * 8;
  for (int j = 0; j < 16; ++j) {
    int kk = j * 4 + kw;            // 0..63
    const float* s = row + kk * 32;
    f32x4 v0 = *reinterpret_cast<const f32x4*>(s);
    f32x4 v1 = *reinterpret_cast<const f32x4*>(s + 4);
    h16x8 o;
#pragma unroll
    for (int q = 0; q < 4; ++q) { o[q] = (_Float16)v0[q]; o[4 + q] = (_Float16)v1[q]; }
    *reinterpret_cast<h16x8*>(Wahs + (((size_t)ct * NKK_A + kk) * 64 + l) * 8) = o;
  }
}

// One-time Gy = yT @ Wys + bias: M=8192 (t*64+b), N=8192 (n'), K=2048, f16 out.
__global__ void __launch_bounds__(512)
gy_gemm(const _Float16* __restrict__ yT, const _Float16* __restrict__ Wys,
        const float* __restrict__ bperm, _Float16* __restrict__ Gy) {
  int tid = threadIdx.x;
  int w = tid >> 6, l = tid & 63;
  int wr = w >> 2, wc = w & 3;
  int br = blockIdx.x & 63, bc = blockIdx.x >> 6;
  const _Float16* abase = yT + ((size_t)(br * 128 + wr * 64 + (l & 15))) * HH + (l >> 4) * 8;
  const _Float16* bbase = Wys + ((size_t)(bc * 16 + wc * 4) * NKK_A) * 512 + l * 8;
  f32x4 acc[4][4] = {};
#pragma unroll 1
  for (int kk = 0; kk < NKK_A; ++kk) {
    h16x8 a0 = *reinterpret_cast<const h16x8*>(abase + (size_t)0 * 16 * HH + kk * 32);
    h16x8 a1 = *reinterpret_cast<const h16x8*>(abase + (size_t)1 * 16 * HH + kk * 32);
    h16x8 a2 = *reinterpret_cast<const h16x8*>(abase + (size_t)2 * 16 * HH + kk * 32);
    h16x8 a3 = *reinterpret_cast<const h16x8*>(abase + (size_t)3 * 16 * HH + kk * 32);
    h16x8 b0 = *reinterpret_cast<const h16x8*>(bbase + ((size_t)0 * NKK_A + kk) * 512);
    h16x8 b1 = *reinterpret_cast<const h16x8*>(bbase + ((size_t)1 * NKK_A + kk) * 512);
    h16x8 b2 = *reinterpret_cast<const h16x8*>(bbase + ((size_t)2 * NKK_A + kk) * 512);
    h16x8 b3 = *reinterpret_cast<const h16x8*>(bbase + ((size_t)3 * NKK_A + kk) * 512);
    acc[0][0] = mfma16(a0, b0, acc[0][0]); acc[0][1] = mfma16(a0, b1, acc[0][1]);
    acc[0][2] = mfma16(a0, b2, acc[0][2]); acc[0][3] = mfma16(a0, b3, acc[0][3]);
    acc[1][0] = mfma16(a1, b0, acc[1][0]); acc[1][1] = mfma16(a1, b1, acc[1][1]);
    acc[1][2] = mfma16(a1, b2, acc[1][2]); acc[1][3] = mfma16(a1, b3, acc[1][3]);
    acc[2][0] = mfma16(a2, b0, acc[2][0]); acc[2][1] = mfma16(a2, b1, acc[2][1]);
    acc[2][2] = mfma16(a2, b2, acc[2][2]); acc[2][3] = mfma16(a2, b3, acc[2][3]);
    acc[3][0] = mfma16(a3, b0, acc[3][0]); acc[3][1] = mfma16(a3, b1, acc[3][1]);
    acc[3][2] = mfma16(a3, b2, acc[3][2]); acc[3][3] = mfma16(a3, b3, acc[3][3]);
  }
#pragma unroll
  for (int q = 0; q < 4; ++q) {
#pragma unroll
    for (int cc = 0; cc < 4; ++cc) {
      int col = (bc * 16 + wc * 4 + cc) * 16 + (l & 15);
      float bv = bperm[col];
      int r0 = br * 128 + wr * 64 + q * 16 + (l >> 4) * 4;
#pragma unroll
      for (int r = 0; r < 4; ++r)
        Gy[(size_t)(r0 + r) * G4H + col] = (_Float16)(acc[q][cc][r] + bv);
    }
  }
}

__global__ void init_state(float* __restrict__ cst, _Float16* __restrict__ hA) {
  int i = blockIdx.x * blockDim.x + threadIdx.x;
  if (i < BB * HH) {
    cst[i] = 0.0f;
    hA[i] = (_Float16)0.0f;
  }
}

// ---------------- per-step kernels ----------------

// q[b,k] = sum_j h[b,j]*W_attr[k,j]  (M=64, N=2048, K=2048), bias folded into kh.
// grid = 256 x 128 thr: (ct, mhalf) blocks -> all 256 CUs busy.
__global__ void __launch_bounds__(128)
qgemm(const _Float16* __restrict__ hIn, const _Float16* __restrict__ Wahs,
      _Float16* __restrict__ qh) {
  int w = threadIdx.x >> 6, l = threadIdx.x & 63;   // w 0..1
  int ct = blockIdx.x >> 1, mh = blockIdx.x & 1;
  const _Float16* bp = Wahs + (size_t)ct * (NKK_A * 512) + l * 8;
  const _Float16* ap = hIn + (size_t)(mh * 32 + w * 16 + (l & 15)) * HH + (l >> 4) * 8;
  f32x4 acc0 = {0.f, 0.f, 0.f, 0.f}, acc1 = {0.f, 0.f, 0.f, 0.f};
  f32x4 acc2 = {0.f, 0.f, 0.f, 0.f}, acc3 = {0.f, 0.f, 0.f, 0.f};
#pragma unroll 2
  for (int kk = 0; kk < NKK_A; kk += 4) {
    h16x8 b0 = *reinterpret_cast<const h16x8*>(bp + (size_t)kk * 512);
    h16x8 b1 = *reinterpret_cast<const h16x8*>(bp + (size_t)(kk + 1) * 512);
    h16x8 b2 = *reinterpret_cast<const h16x8*>(bp + (size_t)(kk + 2) * 512);
    h16x8 b3 = *reinterpret_cast<const h16x8*>(bp + (size_t)(kk + 3) * 512);
    h16x8 a0 = *reinterpret_cast<const h16x8*>(ap + kk * 32);
    h16x8 a1 = *reinterpret_cast<const h16x8*>(ap + (kk + 1) * 32);
    h16x8 a2 = *reinterpret_cast<const h16x8*>(ap + (kk + 2) * 32);
    h16x8 a3 = *reinterpret_cast<const h16x8*>(ap + (kk + 3) * 32);
    acc0 = mfma16(a0, b0, acc0);
    acc1 = mfma16(a1, b1, acc1);
    acc2 = mfma16(a2, b2, acc2);
    acc3 = mfma16(a3, b3, acc3);
  }
  f32x4 acc = (acc0 + acc1) + (acc2 + acc3);
  int col = ct * 16 + (l & 15);
  int rbase = mh * 32 + w * 16 + (l >> 4) * 4;
#pragma unroll
  for (int r = 0; r < 4; ++r)
    qh[(size_t)(rbase + r) * HH + col] = (_Float16)acc[r];
}

// p[b,s] = mask*exp(sum_k V[k]*tanh(kh[b,s,k] + q[b,k]))  (unnormalized softmax weight;
// masked -> 0 exactly, matching exp(-1e5)=0). Fully unrolled, no runtime-indexed arrays.
__global__ void energies(const _Float16* __restrict__ kh, const _Float16* __restrict__ qh,
                         const _Float16* __restrict__ vh, const float* __restrict__ mask,
                         float* __restrict__ pbuf) {
  int b = blockIdx.x >> 5, sg = blockIdx.x & 31;
  int tid = threadIdx.x;
  int sl = tid >> 5, ln = tid & 31;
  int s = sg * 8 + sl;
  const _Float16* row = kh + (size_t)(b * SS + s) * HH + ln * 8;
  const _Float16* qrow = qh + (size_t)b * HH + ln * 8;
  const _Float16* vrow = vh + ln * 8;
  float acc = 0.0f;
#pragma unroll
  for (int ch = 0; ch < 8; ++ch) {
    h16x8 k8 = *reinterpret_cast<const h16x8*>(row + ch * 256);
    h16x8 q8 = *reinterpret_cast<const h16x8*>(qrow + ch * 256);
    h16x8 v8 = *reinterpret_cast<const h16x8*>(vrow + ch * 256);
    h16x8 x8 = k8 + q8;
#pragma unroll
    for (int j = 0; j < 8; ++j) {
      acc += (float)v8[j] * fast_tanh((float)x8[j]);
    }
  }
#pragma unroll
  for (int off = 16; off > 0; off >>= 1) acc += __shfl_xor(acc, off);
  if (ln == 0) {
    float m = mask[b * SS + s];
    pbuf[b * SS + s] = m * fast_exp2(acc * 1.4426950408889634f);
  }
}

// ctx[b,c] = (sum_s p[s]*ev[b,s,c]) / sum_s p[s]. grid = B*4 x 512 thr.
__global__ void __launch_bounds__(512)
ctx_softmax(const float* __restrict__ pbuf, const _Float16* __restrict__ evh,
            _Float16* __restrict__ ctxh, float* __restrict__ outCtx, int t) {
  __shared__ float pb[SS];
  __shared__ float red[4];
  __shared__ float pf[8][512];
  int b = blockIdx.x >> 2, cq = blockIdx.x & 3;
  int tid = threadIdx.x;
  if (tid < SS) {
    float p = pbuf[b * SS + tid];
    pb[tid] = p;
    float ws = p;
#pragma unroll
    for (int off = 32; off > 0; off >>= 1) ws += __shfl_xor(ws, off);
    if ((tid & 63) == 0) red[tid >> 6] = ws;
  }
  __syncthreads();
  float rs = fast_rcp(red[0] + red[1] + red[2] + red[3]);
  int sg = tid >> 6, cs = tid & 63;
  const _Float16* base = evh + ((size_t)b * SS + sg * 32) * HH + cq * 512 + cs * 8;
  float acc[8] = {0.f, 0.f, 0.f, 0.f, 0.f, 0.f, 0.f, 0.f};
#pragma unroll 8
  for (int s = 0; s < 32; ++s) {
    h16x8 v = *reinterpret_cast<const h16x8*>(base + (size_t)s * HH);
    float ps = pb[sg * 32 + s];
#pragma unroll
    for (int j = 0; j < 8; ++j) acc[j] += ps * (float)v[j];
  }
#pragma unroll
  for (int j = 0; j < 8; ++j) pf[sg][cs * 8 + j] = acc[j];
  __syncthreads();
  {
    int c = tid;                    // 0..511
    float sum = pf[0][c] + pf[1][c] + pf[2][c] + pf[3][c]
              + pf[4][c] + pf[5][c] + pf[6][c] + pf[7][c];
    float val = sum * rs;
    outCtx[((size_t)b * TT + t) * HH + cq * 512 + c] = val;
    ctxh[(size_t)b * HH + cq * 512 + c] = (_Float16)val;
  }
}

// gates = Gy[t] (acc init) + h@U^T + ctx@C^T, fused LSTM cell.
// grid = 256 x 512 thr (8 waves = 4 mq x 2 cth). Triple-buffered B staging via
// global_load_lds with counted s_waitcnt vmcnt(4) + raw s_barrier (T3/T4 minimum):
// chunk c+2 staging stays in flight across a full chunk instead of draining at
// the barrier. Schedule: {MFMA(c)} {STAGE(c+2)} {vmcnt(4): c+1 landed} {barrier}.
__global__ void __launch_bounds__(512)
gates_cell(const _Float16* __restrict__ hIn, const _Float16* __restrict__ ctxh,
           const _Float16* __restrict__ Gy, const _Float16* __restrict__ Wgs,
           float* __restrict__ cst, float* __restrict__ outH,
           _Float16* __restrict__ hOut, int t) {
  __shared__ _Float16 Bsm[3][2][16][512];   // [buf][ctgl][slot][lane*8] = 96 KB
  __shared__ float glds[64 * 33];
  int tid = threadIdx.x;
  int w = tid >> 6, l = tid & 63;
  int mq = w >> 1, cth = w & 1;
  int cb = blockIdx.x;

  // stage chunk c (16 kk-slots x 2 ctg = 32 KB, 4 loads per wave) into Bsm[buf]
  auto STAGE = [&](int buf, int c) {
#pragma unroll
    for (int u = 0; u < 4; ++u) {
      int idx = w * 4 + u;            // 0..31
      int ctgl = idx >> 4, slot = idx & 15;
      const _Float16* g = Wgs + (((size_t)(cb * 2 + ctgl) * NKK_G + c * 16 + slot) * 64 + l) * 8;
      __builtin_amdgcn_global_load_lds((GV*)g, (SV*)&Bsm[buf][ctgl][slot][0], 16, 0, 0);
    }
  };

  STAGE(0, 0);
  STAGE(1, 1);

  // acc init from Gy (rows t*64+b, cols n') — overlaps the staging latency.
  int col = cb * 32 + cth * 16 + (l & 15);
  int rb = mq * 16 + (l >> 4) * 4;
  f32x4 acc;
  {
    const _Float16* gy = Gy + ((size_t)(t * 64 + rb)) * G4H + col;
    acc[0] = (float)gy[0];
    acc[1] = (float)gy[(size_t)G4H];
    acc[2] = (float)gy[(size_t)2 * G4H];
    acc[3] = (float)gy[(size_t)3 * G4H];
  }

  size_t arow = (size_t)(mq * 16 + (l & 15)) * HH + (l >> 4) * 8;

  // chunk 0 ready (own chunk-1 loads may stay in flight), all waves rendezvous
  asm volatile("s_waitcnt vmcnt(4)" ::: "memory");
  __builtin_amdgcn_s_barrier();
  __builtin_amdgcn_sched_barrier(0);

#pragma unroll 1
  for (int c = 0; c < 8; ++c) {
    int buf = c % 3;
    const _Float16* a = (c < 4 ? hIn : ctxh) + arow;
    int kloc = (c & 3) * 16;
#pragma unroll
    for (int s = 0; s < 16; ++s) {
      h16x8 bf = *reinterpret_cast<const h16x8*>(&Bsm[buf][cth][s][l * 8]);
      h16x8 af = *reinterpret_cast<const h16x8*>(a + (kloc + s) * 32);
      acc = mfma16(af, bf, acc);
    }
    if (c < 6) {
      STAGE((c + 2) % 3, c + 2);
      asm volatile("s_waitcnt vmcnt(4)" ::: "memory");  // chunk c+1 landed
    } else {
      asm volatile("s_waitcnt vmcnt(0)" ::: "memory");  // tail: drain all
    }
    __builtin_amdgcn_s_barrier();
    __builtin_amdgcn_sched_barrier(0);
  }

  int lcol = cth * 16 + (l & 15);
#pragma unroll
  for (int r = 0; r < 4; ++r)
    glds[(rb + r) * 33 + lcol] = acc[r];
  __syncthreads();
  // cell: 512 threads, one (b, h) each; block covers 8 h-indices.
  int b = tid >> 3, hl = tid & 7;
  int h0 = cb * 8;
  float gi = glds[b * 33 + hl * 4 + 0];
  float gf = glds[b * 33 + hl * 4 + 1];
  float go = glds[b * 33 + hl * 4 + 2];
  float gc = glds[b * 33 + hl * 4 + 3];
  float ig = fast_sig(gi), fg = fast_sig(gf), og = fast_sig(go);
  int ci = b * HH + h0 + hl;
  float cN = ig * fast_tanh(gc) + fg * cst[ci];
  float hN = og * fast_tanh(cN);
  cst[ci] = cN;
  outH[((size_t)b * TT + t) * HH + h0 + hl] = hN;
  hOut[ci] = (_Float16)hN;
}

// ---------------- launcher ----------------

extern "C" void kernel_launch(void* const* d_in, const int* in_sizes, int n_in,
                              void* d_out, int out_size, void* d_ws, size_t ws_size,
                              hipStream_t stream) {
  const float* enc_keys   = (const float*)d_in[0];
  const float* enc_values = (const float*)d_in[1];
  const float* enc_mask   = (const float*)d_in[2];
  const float* y          = (const float*)d_in[3];
  const float* W_attr     = (const float*)d_in[4];
  const float* V_attr     = (const float*)d_in[5];
  const float* b_attr     = (const float*)d_in[6];
  const float* W_y        = (const float*)d_in[7];
  const float* U_h        = (const float*)d_in[8];
  const float* C_ctx      = (const float*)d_in[9];
  const float* bias       = (const float*)d_in[10];

  char* ws = (char*)d_ws;
  size_t off = 0;
  auto alloc = [&](size_t bytes) {
    void* p = ws + off;
    off += (bytes + 255) & ~(size_t)255;
    return p;
  };
  _Float16* kh   = (_Float16*)alloc((size_t)BB * SS * HH * 2);
  _Float16* evh  = (_Float16*)alloc((size_t)BB * SS * HH * 2);
  _Float16* Wahs = (_Float16*)alloc((size_t)HH * HH * 2);
  _Float16* Wgs  = (_Float16*)alloc((size_t)G4H * KSUM * 2);
  _Float16* Wys  = (_Float16*)alloc((size_t)G4H * HH * 2);
  _Float16* Gy   = (_Float16*)alloc((size_t)BB * TT * G4H * 2);
  _Float16* yTh  = (_Float16*)alloc((size_t)BB * TT * HH * 2);
  _Float16* hA   = (_Float16*)alloc((size_t)BB * HH * 2);
  _Float16* hB   = (_Float16*)alloc((size_t)BB * HH * 2);
  _Float16* ctxh = (_Float16*)alloc((size_t)BB * HH * 2);
  _Float16* qh   = (_Float16*)alloc((size_t)BB * HH * 2);
  _Float16* vhb  = (_Float16*)alloc((size_t)HH * 2);
  float* pbuf    = (float*)alloc((size_t)BB * SS * 4);
  float* cst     = (float*)alloc((size_t)BB * HH * 4);
  float* bperm   = (float*)alloc((size_t)G4H * 4);
  (void)ws_size; (void)in_sizes; (void)n_in; (void)out_size;

  float* outH = (float*)d_out;
  float* outCtx = outH + (size_t)BB * TT * HH;

  cvt_keys<<<2048, 256, 0, stream>>>(enc_keys, b_attr, kh, BB * SS * HH / 8);
  cvt_f32_to_f16<<<2048, 256, 0, stream>>>(enc_values, evh, BB * SS * HH / 4);
  cvt_f32_to_f16<<<2, 256, 0, stream>>>(V_attr, vhb, HH / 4);
  build_wahs<<<HH / 16, 256, 0, stream>>>(W_attr, Wahs);
  build_wgs<<<G4H / 16, 256, 0, stream>>>(U_h, C_ctx, bias, Wgs, bperm);
  build_wys<<<G4H / 16, 256, 0, stream>>>(W_y, Wys);
  transpose_y<<<BB * TT, 256, 0, stream>>>(y, yTh);
  gy_gemm<<<2048, 512, 0, stream>>>(yTh, Wys, bperm, Gy);
  init_state<<<(BB * HH + 255) / 256, 256, 0, stream>>>(cst, hA);

  for (int t = 0; t < TT; ++t) {
    const _Float16* hIn = (t & 1) ? hB : hA;
    _Float16* hOut      = (t & 1) ? hA : hB;
    qgemm<<<256, 128, 0, stream>>>(hIn, Wahs, qh);
    energies<<<BB * SS / 8, 256, 0, stream>>>(kh, qh, vhb, enc_mask, pbuf);
    ctx_softmax<<<BB * 4, 512, 0, stream>>>(pbuf, evh, ctxh, outCtx, t);
    gates_cell<<<G4H / 32, 512, 0, stream>>>(hIn, ctxh, Gy, Wgs, cst, outH, hOut, t);
  }
}

// Round 10
// 10258.449 us; speedup vs baseline: 1.0304x; 1.0150x over previous
//
#include <hip/hip_runtime.h>

#define BB 64
#define TT 128
#define SS 256
#define HH 2048
#define G4H 8192
#define KSUM 4096   // per-step GEMM K: [U_h | C_ctx]
#define NKK_G 128   // KSUM/32
#define NKK_A 64    // HH/32

typedef __attribute__((ext_vector_type(4))) float f32x4;
typedef __attribute__((ext_vector_type(8))) _Float16 h16x8;
typedef __attribute__((ext_vector_type(4))) _Float16 h16x4;
typedef __attribute__((ext_vector_type(2))) _Float16 h16x2;

typedef __attribute__((address_space(1))) const void GV;
typedef __attribute__((address_space(3))) void SV;

__device__ __forceinline__ f32x4 mfma16(h16x8 a, h16x8 b, f32x4 c) {
  return __builtin_amdgcn_mfma_f32_16x16x32_f16(a, b, c, 0, 0, 0);
}

__device__ __forceinline__ float fast_exp2(float x) { return __builtin_amdgcn_exp2f(x); }
__device__ __forceinline__ float fast_rcp(float x) { return __builtin_amdgcn_rcpf(x); }
__device__ __forceinline__ float fast_tanh(float x) {
  float e = fast_exp2(x * 2.8853900817779268f);
  return 1.0f - 2.0f * fast_rcp(e + 1.0f);
}
__device__ __forceinline__ float fast_sig(float x) {
  return fast_rcp(1.0f + fast_exp2(x * -1.4426950408889634f));
}

// ---------------- prep kernels ----------------

__global__ void cvt_f32_to_f16(const float* __restrict__ src, _Float16* __restrict__ dst, int n4) {
  int i = blockIdx.x * blockDim.x + threadIdx.x;
  int stride = gridDim.x * blockDim.x;
  for (; i < n4; i += stride) {
    f32x4 v = reinterpret_cast<const f32x4*>(src)[i];
    h16x4 h;
    h[0] = (_Float16)v[0]; h[1] = (_Float16)v[1];
    h[2] = (_Float16)v[2]; h[3] = (_Float16)v[3];
    reinterpret_cast<h16x4*>(dst)[i] = h;
  }
}

// kh[b,s,k] = f16(enc_keys[b,s,k] + b_attr[k])
__global__ void cvt_keys(const float* __restrict__ src, const float* __restrict__ battr,
                         _Float16* __restrict__ dst, int n8) {
  int i = blockIdx.x * blockDim.x + threadIdx.x;
  int stride = gridDim.x * blockDim.x;
  for (; i < n8; i += stride) {
    size_t base = (size_t)i * 8;
    int k = (int)(base & (HH - 1));
    f32x4 v0 = *reinterpret_cast<const f32x4*>(src + base);
    f32x4 v1 = *reinterpret_cast<const f32x4*>(src + base + 4);
    f32x4 b0 = *reinterpret_cast<const f32x4*>(battr + k);
    f32x4 b1 = *reinterpret_cast<const f32x4*>(battr + k + 4);
    h16x8 o;
#pragma unroll
    for (int j = 0; j < 4; ++j) { o[j] = (_Float16)(v0[j] + b0[j]); o[4 + j] = (_Float16)(v1[j] + b1[j]); }
    *reinterpret_cast<h16x8*>(dst + base) = o;
  }
}

// yT[t][b][i] = f16(y[b][t][i])  (row index t*64+b matches Gy rows)
__global__ void transpose_y(const float* __restrict__ y, _Float16* __restrict__ yT) {
  int blk = blockIdx.x;             // B*T blocks
  int b = blk / TT, t = blk - b * TT;
  int i = threadIdx.x * 8;
  const float* s = y + ((size_t)b * TT + t) * HH + i;
  f32x4 v0 = *reinterpret_cast<const f32x4*>(s);
  f32x4 v1 = *reinterpret_cast<const f32x4*>(s + 4);
  h16x8 o;
#pragma unroll
  for (int j = 0; j < 4; ++j) { o[j] = (_Float16)v0[j]; o[4 + j] = (_Float16)v1[j]; }
  *reinterpret_cast<h16x8*>(yT + ((size_t)t * BB + b) * HH + i) = o;
}

// Swizzled B layout: frag(ct, kk, lane, i) = W[ct*16 + (lane&15)][kk*32 + (lane>>4)*8 + i]
// stored at ((ct*NKK + kk)*64 + lane)*8 + i (halves). Wave load at (ct,kk) = 1KB contiguous.

// Wgs: cols n' = 4*h + g (gate-interleaved), rows = [U_h | C_ctx] over K=4096.
__global__ void build_wgs(const float* __restrict__ U, const float* __restrict__ Cc,
                          const float* __restrict__ bias,
                          _Float16* __restrict__ Wgs, float* __restrict__ bperm) {
  int ct = blockIdx.x;              // 0..511
  int kw = threadIdx.x >> 6, l = threadIdx.x & 63;
  int c = ct * 16 + (l & 15);
  int g = c & 3, hidx = c >> 2;
  size_t srow = ((size_t)g * HH + hidx) * HH;
  const float* seg[2] = {U + srow, Cc + srow};
  int koff_lane = (l >> 4) * 8;
  for (int j = 0; j < 32; ++j) {
    int kk = j * 4 + kw;            // 0..127; seg by kk>>6 == j>>4
    const float* s = seg[j >> 4] + (kk & 63) * 32 + koff_lane;
    f32x4 v0 = *reinterpret_cast<const f32x4*>(s);
    f32x4 v1 = *reinterpret_cast<const f32x4*>(s + 4);
    h16x8 o;
#pragma unroll
    for (int q = 0; q < 4; ++q) { o[q] = (_Float16)v0[q]; o[4 + q] = (_Float16)v1[q]; }
    *reinterpret_cast<h16x8*>(Wgs + (((size_t)ct * NKK_G + kk) * 64 + l) * 8) = o;
  }
  if (threadIdx.x < 16) bperm[c] = bias[g * HH + hidx];
}

// Wys: W_y fragments, cols in n' = 4*h + g order, K = 2048.
__global__ void build_wys(const float* __restrict__ Wy, _Float16* __restrict__ Wys) {
  int ct = blockIdx.x;              // 0..511
  int kw = threadIdx.x >> 6, l = threadIdx.x & 63;
  int c = ct * 16 + (l & 15);
  int g = c & 3, hidx = c >> 2;
  const float* row = Wy + ((size_t)g * HH + hidx) * HH + (l >> 4) * 8;
  for (int j = 0; j < 16; ++j) {
    int kk = j * 4 + kw;            // 0..63
    const float* s = row + kk * 32;
    f32x4 v0 = *reinterpret_cast<const f32x4*>(s);
    f32x4 v1 = *reinterpret_cast<const f32x4*>(s + 4);
    h16x8 o;
#pragma unroll
    for (int q = 0; q < 4; ++q) { o[q] = (_Float16)v0[q]; o[4 + q] = (_Float16)v1[q]; }
    *reinterpret_cast<h16x8*>(Wys + (((size_t)ct * NKK_A + kk) * 64 + l) * 8) = o;
  }
}

// Wahs from W_attr [K=2048 rows][H=2048], cols of the GEMM are W_attr rows.
__global__ void build_wahs(const float* __restrict__ W, _Float16* __restrict__ Wahs) {
  int ct = blockIdx.x;              // 0..127
  int kw = threadIdx.x >> 6, l = threadIdx.x & 63;
  int c = ct * 16 + (l & 15);
  const float* row = W + (size_t)c * HH + (l >> 4) * 8;
  for (int j = 0; j < 16; ++j) {
    int kk = j * 4 + kw;            // 0..63
    const float* s = row + kk * 32;
    f32x4 v0 = *reinterpret_cast<const f32x4*>(s);
    f32x4 v1 = *reinterpret_cast<const f32x4*>(s + 4);
    h16x8 o;
#pragma unroll
    for (int q = 0; q < 4; ++q) { o[q] = (_Float16)v0[q]; o[4 + q] = (_Float16)v1[q]; }
    *reinterpret_cast<h16x8*>(Wahs + (((size_t)ct * NKK_A + kk) * 64 + l) * 8) = o;
  }
}

// One-time Gy = yT @ Wys + bias: M=8192 (t*64+b), N=8192 (n'), K=2048, f16 out.
__global__ void __launch_bounds__(512)
gy_gemm(const _Float16* __restrict__ yT, const _Float16* __restrict__ Wys,
        const float* __restrict__ bperm, _Float16* __restrict__ Gy) {
  int tid = threadIdx.x;
  int w = tid >> 6, l = tid & 63;
  int wr = w >> 2, wc = w & 3;
  int br = blockIdx.x & 63, bc = blockIdx.x >> 6;
  const _Float16* abase = yT + ((size_t)(br * 128 + wr * 64 + (l & 15))) * HH + (l >> 4) * 8;
  const _Float16* bbase = Wys + ((size_t)(bc * 16 + wc * 4) * NKK_A) * 512 + l * 8;
  f32x4 acc[4][4] = {};
#pragma unroll 1
  for (int kk = 0; kk < NKK_A; ++kk) {
    h16x8 a0 = *reinterpret_cast<const h16x8*>(abase + (size_t)0 * 16 * HH + kk * 32);
    h16x8 a1 = *reinterpret_cast<const h16x8*>(abase + (size_t)1 * 16 * HH + kk * 32);
    h16x8 a2 = *reinterpret_cast<const h16x8*>(abase + (size_t)2 * 16 * HH + kk * 32);
    h16x8 a3 = *reinterpret_cast<const h16x8*>(abase + (size_t)3 * 16 * HH + kk * 32);
    h16x8 b0 = *reinterpret_cast<const h16x8*>(bbase + ((size_t)0 * NKK_A + kk) * 512);
    h16x8 b1 = *reinterpret_cast<const h16x8*>(bbase + ((size_t)1 * NKK_A + kk) * 512);
    h16x8 b2 = *reinterpret_cast<const h16x8*>(bbase + ((size_t)2 * NKK_A + kk) * 512);
    h16x8 b3 = *reinterpret_cast<const h16x8*>(bbase + ((size_t)3 * NKK_A + kk) * 512);
    acc[0][0] = mfma16(a0, b0, acc[0][0]); acc[0][1] = mfma16(a0, b1, acc[0][1]);
    acc[0][2] = mfma16(a0, b2, acc[0][2]); acc[0][3] = mfma16(a0, b3, acc[0][3]);
    acc[1][0] = mfma16(a1, b0, acc[1][0]); acc[1][1] = mfma16(a1, b1, acc[1][1]);
    acc[1][2] = mfma16(a1, b2, acc[1][2]); acc[1][3] = mfma16(a1, b3, acc[1][3]);
    acc[2][0] = mfma16(a2, b0, acc[2][0]); acc[2][1] = mfma16(a2, b1, acc[2][1]);
    acc[2][2] = mfma16(a2, b2, acc[2][2]); acc[2][3] = mfma16(a2, b3, acc[2][3]);
    acc[3][0] = mfma16(a3, b0, acc[3][0]); acc[3][1] = mfma16(a3, b1, acc[3][1]);
    acc[3][2] = mfma16(a3, b2, acc[3][2]); acc[3][3] = mfma16(a3, b3, acc[3][3]);
  }
#pragma unroll
  for (int q = 0; q < 4; ++q) {
#pragma unroll
    for (int cc = 0; cc < 4; ++cc) {
      int col = (bc * 16 + wc * 4 + cc) * 16 + (l & 15);
      float bv = bperm[col];
      int r0 = br * 128 + wr * 64 + q * 16 + (l >> 4) * 4;
#pragma unroll
      for (int r = 0; r < 4; ++r)
        Gy[(size_t)(r0 + r) * G4H + col] = (_Float16)(acc[q][cc][r] + bv);
    }
  }
}

__global__ void init_state(float* __restrict__ cst, _Float16* __restrict__ hA) {
  int i = blockIdx.x * blockDim.x + threadIdx.x;
  if (i < BB * HH) {
    cst[i] = 0.0f;
    hA[i] = (_Float16)0.0f;
  }
}

// ---------------- per-step kernels ----------------

// q[b,k] = sum_j h[b,j]*W_attr[k,j]  (M=64, N=2048, K=2048), bias folded into kh.
// grid = 256 x 128 thr: (ct, mhalf) blocks -> all 256 CUs busy.
__global__ void __launch_bounds__(128)
qgemm(const _Float16* __restrict__ hIn, const _Float16* __restrict__ Wahs,
      _Float16* __restrict__ qh) {
  int w = threadIdx.x >> 6, l = threadIdx.x & 63;   // w 0..1
  int ct = blockIdx.x >> 1, mh = blockIdx.x & 1;
  const _Float16* bp = Wahs + (size_t)ct * (NKK_A * 512) + l * 8;
  const _Float16* ap = hIn + (size_t)(mh * 32 + w * 16 + (l & 15)) * HH + (l >> 4) * 8;
  f32x4 acc0 = {0.f, 0.f, 0.f, 0.f}, acc1 = {0.f, 0.f, 0.f, 0.f};
  f32x4 acc2 = {0.f, 0.f, 0.f, 0.f}, acc3 = {0.f, 0.f, 0.f, 0.f};
#pragma unroll 2
  for (int kk = 0; kk < NKK_A; kk += 4) {
    h16x8 b0 = *reinterpret_cast<const h16x8*>(bp + (size_t)kk * 512);
    h16x8 b1 = *reinterpret_cast<const h16x8*>(bp + (size_t)(kk + 1) * 512);
    h16x8 b2 = *reinterpret_cast<const h16x8*>(bp + (size_t)(kk + 2) * 512);
    h16x8 b3 = *reinterpret_cast<const h16x8*>(bp + (size_t)(kk + 3) * 512);
    h16x8 a0 = *reinterpret_cast<const h16x8*>(ap + kk * 32);
    h16x8 a1 = *reinterpret_cast<const h16x8*>(ap + (kk + 1) * 32);
    h16x8 a2 = *reinterpret_cast<const h16x8*>(ap + (kk + 2) * 32);
    h16x8 a3 = *reinterpret_cast<const h16x8*>(ap + (kk + 3) * 32);
    acc0 = mfma16(a0, b0, acc0);
    acc1 = mfma16(a1, b1, acc1);
    acc2 = mfma16(a2, b2, acc2);
    acc3 = mfma16(a3, b3, acc3);
  }
  f32x4 acc = (acc0 + acc1) + (acc2 + acc3);
  int col = ct * 16 + (l & 15);
  int rbase = mh * 32 + w * 16 + (l >> 4) * 4;
#pragma unroll
  for (int r = 0; r < 4; ++r)
    qh[(size_t)(rbase + r) * HH + col] = (_Float16)acc[r];
}

// p[b,s] = mask*exp(sum_k V[k]*tanh(kh[b,s,k] + q[b,k]))  (unnormalized softmax weight;
// masked -> 0 exactly, matching exp(-1e5)=0). Fully unrolled, no runtime-indexed arrays.
__global__ void energies(const _Float16* __restrict__ kh, const _Float16* __restrict__ qh,
                         const _Float16* __restrict__ vh, const float* __restrict__ mask,
                         float* __restrict__ pbuf) {
  int b = blockIdx.x >> 5, sg = blockIdx.x & 31;
  int tid = threadIdx.x;
  int sl = tid >> 5, ln = tid & 31;
  int s = sg * 8 + sl;
  const _Float16* row = kh + (size_t)(b * SS + s) * HH + ln * 8;
  const _Float16* qrow = qh + (size_t)b * HH + ln * 8;
  const _Float16* vrow = vh + ln * 8;
  float acc = 0.0f;
#pragma unroll
  for (int ch = 0; ch < 8; ++ch) {
    h16x8 k8 = *reinterpret_cast<const h16x8*>(row + ch * 256);
    h16x8 q8 = *reinterpret_cast<const h16x8*>(qrow + ch * 256);
    h16x8 v8 = *reinterpret_cast<const h16x8*>(vrow + ch * 256);
    h16x8 x8 = k8 + q8;
#pragma unroll
    for (int j = 0; j < 8; ++j) {
      acc += (float)v8[j] * fast_tanh((float)x8[j]);
    }
  }
#pragma unroll
  for (int off = 16; off > 0; off >>= 1) acc += __shfl_xor(acc, off);
  if (ln == 0) {
    float m = mask[b * SS + s];
    pbuf[b * SS + s] = m * fast_exp2(acc * 1.4426950408889634f);
  }
}

// ctx[b,c] = (sum_s p[s]*ev[b,s,c]) / sum_s p[s]. grid = B*4 x 512 thr.
__global__ void __launch_bounds__(512)
ctx_softmax(const float* __restrict__ pbuf, const _Float16* __restrict__ evh,
            _Float16* __restrict__ ctxh, float* __restrict__ outCtx, int t) {
  __shared__ float pb[SS];
  __shared__ float red[4];
  __shared__ float pf[8][512];
  int b = blockIdx.x >> 2, cq = blockIdx.x & 3;
  int tid = threadIdx.x;
  if (tid < SS) {
    float p = pbuf[b * SS + tid];
    pb[tid] = p;
    float ws = p;
#pragma unroll
    for (int off = 32; off > 0; off >>= 1) ws += __shfl_xor(ws, off);
    if ((tid & 63) == 0) red[tid >> 6] = ws;
  }
  __syncthreads();
  float rs = fast_rcp(red[0] + red[1] + red[2] + red[3]);
  int sg = tid >> 6, cs = tid & 63;
  const _Float16* base = evh + ((size_t)b * SS + sg * 32) * HH + cq * 512 + cs * 8;
  float acc[8] = {0.f, 0.f, 0.f, 0.f, 0.f, 0.f, 0.f, 0.f};
#pragma unroll 8
  for (int s = 0; s < 32; ++s) {
    h16x8 v = *reinterpret_cast<const h16x8*>(base + (size_t)s * HH);
    float ps = pb[sg * 32 + s];
#pragma unroll
    for (int j = 0; j < 8; ++j) acc[j] += ps * (float)v[j];
  }
#pragma unroll
  for (int j = 0; j < 8; ++j) pf[sg][cs * 8 + j] = acc[j];
  __syncthreads();
  {
    int c = tid;                    // 0..511
    float sum = pf[0][c] + pf[1][c] + pf[2][c] + pf[3][c]
              + pf[4][c] + pf[5][c] + pf[6][c] + pf[7][c];
    float val = sum * rs;
    outCtx[((size_t)b * TT + t) * HH + cq * 512 + c] = val;
    ctxh[(size_t)b * HH + cq * 512 + c] = (_Float16)val;
  }
}

// gates = Gy[t] (acc init) + h@U^T + ctx@C^T, fused LSTM cell.
// grid = 512 x 256 thr (4 waves = mq 0..3), 16-col slices, ~52 KB LDS -> 2 blocks/CU:
// one block's MFMA phase covers the other's stage-wait (m114 wave-overlap).
// Triple-buffered staging + counted vmcnt(4) + raw s_barrier as R9.
__global__ void __launch_bounds__(256)
gates_cell(const _Float16* __restrict__ hIn, const _Float16* __restrict__ ctxh,
           const _Float16* __restrict__ Gy, const _Float16* __restrict__ Wgs,
           float* __restrict__ cst, float* __restrict__ outH,
           _Float16* __restrict__ hOut, int t) {
  __shared__ _Float16 Bsm[3][16][512];   // [buf][slot][lane*8] = 48 KB
  __shared__ float glds[64 * 17];        // 16 cols (+1 pad) x 64 rows
  int tid = threadIdx.x;
  int w = tid >> 6, l = tid & 63;        // w = mq 0..3
  int cb = blockIdx.x;                   // 16-col tile index 0..511

  // stage chunk c (16 kk-slots x 1 KB = 16 KB, 4 loads per wave) into Bsm[buf]
  auto STAGE = [&](int buf, int c) {
#pragma unroll
    for (int u = 0; u < 4; ++u) {
      int slot = w * 4 + u;              // 0..15
      const _Float16* g = Wgs + (((size_t)cb * NKK_G + c * 16 + slot) * 64 + l) * 8;
      __builtin_amdgcn_global_load_lds((GV*)g, (SV*)&Bsm[buf][slot][0], 16, 0, 0);
    }
  };

  STAGE(0, 0);
  STAGE(1, 1);

  // acc init from Gy (rows t*64+b, cols n') — overlaps the staging latency.
  int col = cb * 16 + (l & 15);
  int rb = w * 16 + (l >> 4) * 4;
  f32x4 acc;
  {
    const _Float16* gy = Gy + ((size_t)(t * 64 + rb)) * G4H + col;
    acc[0] = (float)gy[0];
    acc[1] = (float)gy[(size_t)G4H];
    acc[2] = (float)gy[(size_t)2 * G4H];
    acc[3] = (float)gy[(size_t)3 * G4H];
  }

  size_t arow = (size_t)(w * 16 + (l & 15)) * HH + (l >> 4) * 8;

  // chunk 0 ready (own chunk-1 loads may stay in flight), all waves rendezvous
  asm volatile("s_waitcnt vmcnt(4)" ::: "memory");
  __builtin_amdgcn_s_barrier();
  __builtin_amdgcn_sched_barrier(0);

#pragma unroll 1
  for (int c = 0; c < 8; ++c) {
    int buf = c % 3;
    const _Float16* a = (c < 4 ? hIn : ctxh) + arow;
    int kloc = (c & 3) * 16;
#pragma unroll
    for (int s = 0; s < 16; ++s) {
      h16x8 bf = *reinterpret_cast<const h16x8*>(&Bsm[buf][s][l * 8]);
      h16x8 af = *reinterpret_cast<const h16x8*>(a + (kloc + s) * 32);
      acc = mfma16(af, bf, acc);
    }
    if (c < 6) {
      STAGE((c + 2) % 3, c + 2);
      asm volatile("s_waitcnt vmcnt(4)" ::: "memory");  // chunk c+1 landed
    } else {
      asm volatile("s_waitcnt vmcnt(0)" ::: "memory");  // tail: drain all
    }
    __builtin_amdgcn_s_barrier();
    __builtin_amdgcn_sched_barrier(0);
  }

  int lcol = l & 15;
#pragma unroll
  for (int r = 0; r < 4; ++r)
    glds[(rb + r) * 17 + lcol] = acc[r];
  __syncthreads();
  // cell: 256 threads, one (b, h) each; block covers 4 h-indices.
  int b = tid >> 2, hl = tid & 3;
  int h0 = cb * 4;
  float gi = glds[b * 17 + hl * 4 + 0];
  float gf = glds[b * 17 + hl * 4 + 1];
  float go = glds[b * 17 + hl * 4 + 2];
  float gc = glds[b * 17 + hl * 4 + 3];
  float ig = fast_sig(gi), fg = fast_sig(gf), og = fast_sig(go);
  int ci = b * HH + h0 + hl;
  float cN = ig * fast_tanh(gc) + fg * cst[ci];
  float hN = og * fast_tanh(cN);
  cst[ci] = cN;
  outH[((size_t)b * TT + t) * HH + h0 + hl] = hN;
  hOut[ci] = (_Float16)hN;
}

// ---------------- launcher ----------------

extern "C" void kernel_launch(void* const* d_in, const int* in_sizes, int n_in,
                              void* d_out, int out_size, void* d_ws, size_t ws_size,
                              hipStream_t stream) {
  const float* enc_keys   = (const float*)d_in[0];
  const float* enc_values = (const float*)d_in[1];
  const float* enc_mask   = (const float*)d_in[2];
  const float* y          = (const float*)d_in[3];
  const float* W_attr     = (const float*)d_in[4];
  const float* V_attr     = (const float*)d_in[5];
  const float* b_attr     = (const float*)d_in[6];
  const float* W_y        = (const float*)d_in[7];
  const float* U_h        = (const float*)d_in[8];
  const float* C_ctx      = (const float*)d_in[9];
  const float* bias       = (const float*)d_in[10];

  char* ws = (char*)d_ws;
  size_t off = 0;
  auto alloc = [&](size_t bytes) {
    void* p = ws + off;
    off += (bytes + 255) & ~(size_t)255;
    return p;
  };
  _Float16* kh   = (_Float16*)alloc((size_t)BB * SS * HH * 2);
  _Float16* evh  = (_Float16*)alloc((size_t)BB * SS * HH * 2);
  _Float16* Wahs = (_Float16*)alloc((size_t)HH * HH * 2);
  _Float16* Wgs  = (_Float16*)alloc((size_t)G4H * KSUM * 2);
  _Float16* Wys  = (_Float16*)alloc((size_t)G4H * HH * 2);
  _Float16* Gy   = (_Float16*)alloc((size_t)BB * TT * G4H * 2);
  _Float16* yTh  = (_Float16*)alloc((size_t)BB * TT * HH * 2);
  _Float16* hA   = (_Float16*)alloc((size_t)BB * HH * 2);
  _Float16* hB   = (_Float16*)alloc((size_t)BB * HH * 2);
  _Float16* ctxh = (_Float16*)alloc((size_t)BB * HH * 2);
  _Float16* qh   = (_Float16*)alloc((size_t)BB * HH * 2);
  _Float16* vhb  = (_Float16*)alloc((size_t)HH * 2);
  float* pbuf    = (float*)alloc((size_t)BB * SS * 4);
  float* cst     = (float*)alloc((size_t)BB * HH * 4);
  float* bperm   = (float*)alloc((size_t)G4H * 4);
  (void)ws_size; (void)in_sizes; (void)n_in; (void)out_size;

  float* outH = (float*)d_out;
  float* outCtx = outH + (size_t)BB * TT * HH;

  cvt_keys<<<2048, 256, 0, stream>>>(enc_keys, b_attr, kh, BB * SS * HH / 8);
  cvt_f32_to_f16<<<2048, 256, 0, stream>>>(enc_values, evh, BB * SS * HH / 4);
  cvt_f32_to_f16<<<2, 256, 0, stream>>>(V_attr, vhb, HH / 4);
  build_wahs<<<HH / 16, 256, 0, stream>>>(W_attr, Wahs);
  build_wgs<<<G4H / 16, 256, 0, stream>>>(U_h, C_ctx, bias, Wgs, bperm);
  build_wys<<<G4H / 16, 256, 0, stream>>>(W_y, Wys);
  transpose_y<<<BB * TT, 256, 0, stream>>>(y, yTh);
  gy_gemm<<<2048, 512, 0, stream>>>(yTh, Wys, bperm, Gy);
  init_state<<<(BB * HH + 255) / 256, 256, 0, stream>>>(cst, hA);

  for (int t = 0; t < TT; ++t) {
    const _Float16* hIn = (t & 1) ? hB : hA;
    _Float16* hOut      = (t & 1) ? hA : hB;
    qgemm<<<256, 128, 0, stream>>>(hIn, Wahs, qh);
    energies<<<BB * SS / 8, 256, 0, stream>>>(kh, qh, vhb, enc_mask, pbuf);
    ctx_softmax<<<BB * 4, 512, 0, stream>>>(pbuf, evh, ctxh, outCtx, t);
    gates_cell<<<512, 256, 0, stream>>>(hIn, ctxh, Gy, Wgs, cst, outH, hOut, t);
  }
}